// Round 1
// baseline (117.043 us; speedup 1.0000x reference)
//
#include <hip/hip_runtime.h>
#include <hip/hip_bf16.h>

// RelationalDistMult: B=8, N=1024, DE=128, R=8, DR=64, D=192.
// scores[b,r,n,m] = sum_k w[r,k]*node[b,n,k]*node[b,m,k] + c[b,r]
//   c[b,r] = sum_d w[r,DE+d]*rel[b,r,d]^2
// out = sigmoid(scores) f32 [B,R,N,N] = 256 MB  -> HBM-write-bound
// (fill kernels measure ~7 TB/s => store roofline ~38 us).
//
// Round 4: split into pack + compute.
//  - rdm_pack: writes bf16 operands into workspace in MFMA-fragment-permuted
//    order: scaled[b][r] (w[r,k]*node, 16 MB) and raw[b] (2 MB), plus c[b*8+r].
//    Each (16-row-group g, kk) fragment chunk is a contiguous 1 KB block in
//    lane order, so the main kernel's operand loads are single fully-coalesced
//    global_load_dwordx4 per wave. Also computes c[b,r] once.
//  - rdm4: NO LDS, NO barriers, NO conversions. A-fragments (raw m-rows,
//    64 VGPRs) are loaded once and reused across all 8 r. Per r: 8 contiguous
//    B-fragment loads (L2-resident: 2.25 MB/XCD via b=blockIdx&7 pinning),
//    32 MFMAs, 32 sigmoids, 8 nontemporal float4 stores. nt stores keep the
//    output stream from evicting the packed operands out of L2.
//  - Waves fully independent -> stores issue continuously (no post-barrier
//    bursts), which is what the store-bound roofline needs.

typedef __attribute__((ext_vector_type(8))) short bf16x8;
typedef __attribute__((ext_vector_type(4))) float f32x4;

constexpr int Bc = 8, Nc = 1024, DEc = 128, Rc = 8, DRc = 64, Dc = 192;
constexpr int TILE = 128;

// workspace layout (bytes):
//   [0, 16M)      : scaled bf16 [8][8][131072]  (fragment-permuted per (b,r))
//   [16M, 18M)    : raw    bf16 [8][131072]     (fragment-permuted per b)
//   [18M, 18M+256): c f32 [64]
constexpr size_t WS_SCALED_B = 16u * 1024 * 1024;
constexpr size_t WS_RAW_B    = 2u * 1024 * 1024;
constexpr size_t WS_C_B      = 256;

static __device__ __forceinline__ unsigned short f2bf(float x) {
    __hip_bfloat16 h = __float2bfloat16(x);
    return *reinterpret_cast<unsigned short*>(&h);
}

static __device__ __forceinline__ float fast_sigmoid(float x) {
    // sigmoid(x) = 1 / (1 + 2^(-x*log2e)); v_exp_f32 computes 2^x.
    float e;
    asm("v_exp_f32 %0, %1" : "=v"(e) : "v"(x * -1.44269504f));
    float s;
    asm("v_rcp_f32 %0, %1" : "=v"(s) : "v"(e + 1.0f));
    return s;
}

// ---------------------------------------------------------------------------
// Pack kernel: one wave per (b, g, kk); g = 16-row group (0..63), kk = k-step
// (0..3). Lane l holds elements (n = g*16 + (l&15), k = kk*32 + (l>>4)*8 + j),
// j=0..7 -- exactly the mfma_f32_16x16x32_bf16 A/B fragment layout. The chunk
// for (g,kk) is stored at elem offset (g*4+kk)*512 + l*8: contiguous 1 KB per
// wave store, contiguous 1 KB per wave load in rdm4.
// ---------------------------------------------------------------------------
__global__ __launch_bounds__(256) void rdm_pack(
    const float* __restrict__ node,   // [B,N,DE]
    const float* __restrict__ rel,    // [B,R,DR]
    const float* __restrict__ w,      // [R,D]
    unsigned short* __restrict__ pscaled,  // [8][8][131072]
    unsigned short* __restrict__ praw,     // [8][131072]
    float* __restrict__ pc)                // [64]
{
    const int wid  = blockIdx.x * 4 + (threadIdx.x >> 6);  // 0..2047
    const int lane = threadIdx.x & 63;
    const int kk = wid & 3;
    const int g  = (wid >> 2) & 63;
    const int b  = wid >> 8;                               // 0..7

    const int n  = g * 16 + (lane & 15);
    const int k0 = kk * 32 + (lane >> 4) * 8;

    const float* np = node + ((long)b * Nc + n) * DEc + k0;
    const float4 v0 = *(const float4*)np;
    const float4 v1 = *(const float4*)(np + 4);

    const long chunk = ((long)(g * 4 + kk) * 64 + lane) * 8;  // elems in plane

    // raw bf16 (A operand source)
    bf16x8 rv;
    rv[0] = (short)f2bf(v0.x); rv[1] = (short)f2bf(v0.y);
    rv[2] = (short)f2bf(v0.z); rv[3] = (short)f2bf(v0.w);
    rv[4] = (short)f2bf(v1.x); rv[5] = (short)f2bf(v1.y);
    rv[6] = (short)f2bf(v1.z); rv[7] = (short)f2bf(v1.w);
    *(bf16x8*)(praw + (long)b * 131072 + chunk) = rv;

    // scaled bf16 per r (B operand source)
    #pragma unroll
    for (int r = 0; r < Rc; ++r) {
        const float* wp = w + r * Dc + k0;
        const float4 w0 = *(const float4*)wp;
        const float4 w1 = *(const float4*)(wp + 4);
        bf16x8 sv;
        sv[0] = (short)f2bf(v0.x * w0.x); sv[1] = (short)f2bf(v0.y * w0.y);
        sv[2] = (short)f2bf(v0.z * w0.z); sv[3] = (short)f2bf(v0.w * w0.w);
        sv[4] = (short)f2bf(v1.x * w1.x); sv[5] = (short)f2bf(v1.y * w1.y);
        sv[6] = (short)f2bf(v1.z * w1.z); sv[7] = (short)f2bf(v1.w * w1.w);
        *(bf16x8*)(pscaled + (long)(b * Rc + r) * 131072 + chunk) = sv;
    }

    // c[b,r]: waves with g==0 handle r = 2*kk, 2*kk+1 (lane-parallel over DR=64)
    if (g == 0) {
        #pragma unroll
        for (int q = 0; q < 2; ++q) {
            const int rr = kk * 2 + q;
            const float wv = w[rr * Dc + DEc + lane];
            const float rv2 = rel[((long)b * Rc + rr) * DRc + lane];
            float cv = wv * rv2 * rv2;
            #pragma unroll
            for (int o = 32; o > 0; o >>= 1) cv += __shfl_xor(cv, o, 64);
            if (lane == 0) pc[b * Rc + rr] = cv;
        }
    }
}

// ---------------------------------------------------------------------------
// Main kernel: 1024 blocks x 256 threads (4 waves). Block tile 128(m) x 64(n),
// wave tile 64(m) x 32(n), all 8 r per block. No LDS, no barriers.
// ---------------------------------------------------------------------------
__global__ __launch_bounds__(256, 2) void rdm4(
    const unsigned short* __restrict__ pscaled,
    const unsigned short* __restrict__ praw,
    const float* __restrict__ pc,
    float* __restrict__ out)
{
    const int lin = blockIdx.x;
    const int b   = lin & 7;           // XCD-major: packed data L2-resident/XCD
    const int t   = lin >> 3;          // 0..127
    const int nt  = t & 15;            // 16 n-tiles of 64
    const int mt  = t >> 4;            // 8  m-tiles of 128
    const int n0  = nt * 64;
    const int m0  = mt * 128;

    const int tid  = threadIdx.x;
    const int lane = tid & 63;
    const int wid  = tid >> 6;         // 0..3
    const int wm0  = (wid >> 1) * 64;  // wave m offset in block tile
    const int wn0  = (wid & 1) * 32;   // wave n offset in block tile
    const int lr   = lane & 15;

    // c[b, 0..7]
    const float4 cA = *(const float4*)(pc + b * Rc);
    const float4 cB = *(const float4*)(pc + b * Rc + 4);
    const float carr[8] = {cA.x, cA.y, cA.z, cA.w, cB.x, cB.y, cB.z, cB.w};

    // A fragments (raw m-rows): 16 contiguous-1KB loads, reused for all 8 r.
    const unsigned short* rawb = praw + (long)b * 131072;
    bf16x8 afr[4][4];                  // [kk][mi]
    #pragma unroll
    for (int mi = 0; mi < 4; ++mi) {
        const int gm = ((m0 + wm0) >> 4) + mi;
        #pragma unroll
        for (int kk = 0; kk < 4; ++kk)
            afr[kk][mi] = *(const bf16x8*)(rawb + ((long)(gm * 4 + kk) * 64 + lane) * 8);
    }

    const int gn = (n0 + wn0) >> 4;
    float* outb = out + ((long)b * Rc) * Nc * Nc;

    #pragma unroll
    for (int r = 0; r < Rc; ++r) {
        const unsigned short* sb = pscaled + (long)(b * Rc + r) * 131072;

        // B fragments (scaled n-rows): 8 contiguous-1KB loads.
        bf16x8 bfr[4][2];              // [kk][ni]
        #pragma unroll
        for (int ni = 0; ni < 2; ++ni) {
            #pragma unroll
            for (int kk = 0; kk < 4; ++kk)
                bfr[kk][ni] = *(const bf16x8*)(sb + ((long)((gn + ni) * 4 + kk) * 64 + lane) * 8);
        }

        f32x4 acc[4][2] = {};
        #pragma unroll
        for (int kk = 0; kk < 4; ++kk)
            #pragma unroll
            for (int mi = 0; mi < 4; ++mi)
                #pragma unroll
                for (int ni = 0; ni < 2; ++ni)
                    acc[mi][ni] = __builtin_amdgcn_mfma_f32_16x16x32_bf16(
                        afr[kk][mi], bfr[kk][ni], acc[mi][ni], 0, 0, 0);

        const float c = carr[r];
        float* outr = outb + ((long)r << 20);
        #pragma unroll
        for (int mi = 0; mi < 4; ++mi) {
            #pragma unroll
            for (int ni = 0; ni < 2; ++ni) {
                const int n = n0 + wn0 + ni * 16 + lr;
                const int m = m0 + wm0 + mi * 16 + (lane >> 4) * 4;
                f32x4 v;
                v[0] = fast_sigmoid(acc[mi][ni][0] + c);
                v[1] = fast_sigmoid(acc[mi][ni][1] + c);
                v[2] = fast_sigmoid(acc[mi][ni][2] + c);
                v[3] = fast_sigmoid(acc[mi][ni][3] + c);
                // nt: streaming store, don't evict packed operands from L2
                __builtin_nontemporal_store(v, (f32x4*)(outr + (long)n * Nc + m));
            }
        }
    }
}

// ---------------------------------------------------------------------------
// Fallback (round-3 verified kernel) if workspace is too small.
// ---------------------------------------------------------------------------
__global__ __launch_bounds__(512, 4) void rdm3(
    const float* __restrict__ node,
    const float* __restrict__ rel,
    const float* __restrict__ w,
    float* __restrict__ out)
{
    __shared__ unsigned short As[TILE * TILE];
    __shared__ unsigned short Bs[TILE * TILE];

    const int lin = blockIdx.x;
    const int b   = lin & 7;
    const int r   = (lin >> 3) & 7;
    const int t   = lin >> 6;
    const int ntile = t >> 3;
    const int mtile = t & 7;
    const int n0 = ntile * TILE;
    const int m0 = mtile * TILE;

    const int tid  = threadIdx.x;
    const int lane = tid & 63;
    const int wid  = tid >> 6;

    const float* wrp   = w + r * Dc;
    const float* relbr = rel + ((long)b * Rc + r) * DRc;

    float cv = wrp[DEc + lane] * relbr[lane] * relbr[lane];
    #pragma unroll
    for (int o = 32; o > 0; o >>= 1) cv += __shfl_xor(cv, o, 64);
    const float c = cv;

    const float* nodeb = node + (long)b * Nc * DEc;
    const int col4 = (tid & 31) * 4;
    const int row0 = tid >> 5;
    const float4 wv4 = *(const float4*)(wrp + col4);

    #pragma unroll
    for (int p = 0; p < 8; ++p) {
        const int row = row0 + p * 16;
        const float4 av = *(const float4*)(nodeb + (long)(n0 + row) * DEc + col4);
        const float4 bv = *(const float4*)(nodeb + (long)(m0 + row) * DEc + col4);
        const int e = (row * TILE + col4) ^ ((row & 7) << 3);
        union { ushort4 u4; unsigned short h[4]; } pa, pb;
        pa.h[0] = f2bf(av.x * wv4.x);
        pa.h[1] = f2bf(av.y * wv4.y);
        pa.h[2] = f2bf(av.z * wv4.z);
        pa.h[3] = f2bf(av.w * wv4.w);
        pb.h[0] = f2bf(bv.x);
        pb.h[1] = f2bf(bv.y);
        pb.h[2] = f2bf(bv.z);
        pb.h[3] = f2bf(bv.w);
        *(ushort4*)&As[e] = pa.u4;
        *(ushort4*)&Bs[e] = pb.u4;
    }
    __syncthreads();

    const int wm0 = (wid >> 2) * 64;
    const int wn0 = (wid & 3) * 32;
    const int lr  = lane & 15;
    const int lk  = (lane >> 4) * 8;

    f32x4 acc[4][2] = {};

    #pragma unroll
    for (int kk = 0; kk < 4; ++kk) {
        bf16x8 afr[4], bfr[2];
        #pragma unroll
        for (int mi = 0; mi < 4; ++mi) {
            const int rowA = wm0 + mi * 16 + lr;
            afr[mi] = *(const bf16x8*)&Bs[(rowA * TILE + kk * 32 + lk) ^ ((rowA & 7) << 3)];
        }
        #pragma unroll
        for (int ni = 0; ni < 2; ++ni) {
            const int rowB = wn0 + ni * 16 + lr;
            bfr[ni] = *(const bf16x8*)&As[(rowB * TILE + kk * 32 + lk) ^ ((rowB & 7) << 3)];
        }
        #pragma unroll
        for (int mi = 0; mi < 4; ++mi)
            #pragma unroll
            for (int ni = 0; ni < 2; ++ni)
                acc[mi][ni] = __builtin_amdgcn_mfma_f32_16x16x32_bf16(
                    afr[mi], bfr[ni], acc[mi][ni], 0, 0, 0);
    }

    float* outbr = out + (long)(b * Rc + r) * Nc * Nc;
    #pragma unroll
    for (int mi = 0; mi < 4; ++mi) {
        #pragma unroll
        for (int ni = 0; ni < 2; ++ni) {
            const int n = n0 + wn0 + ni * 16 + lr;
            const int m = m0 + wm0 + mi * 16 + (lane >> 4) * 4;
            float4 v;
            v.x = fast_sigmoid(acc[mi][ni][0] + c);
            v.y = fast_sigmoid(acc[mi][ni][1] + c);
            v.z = fast_sigmoid(acc[mi][ni][2] + c);
            v.w = fast_sigmoid(acc[mi][ni][3] + c);
            *(float4*)(outbr + (long)n * Nc + m) = v;
        }
    }
}

extern "C" void kernel_launch(void* const* d_in, const int* in_sizes, int n_in,
                              void* d_out, int out_size, void* d_ws, size_t ws_size,
                              hipStream_t stream) {
    const float* node = (const float*)d_in[0];  // [8,1024,128]
    const float* rel  = (const float*)d_in[1];  // [8,8,64]
    const float* w    = (const float*)d_in[2];  // [8,192]
    float* out = (float*)d_out;                 // [8,8,1024,1024]

    const size_t need = WS_SCALED_B + WS_RAW_B + WS_C_B;
    if (d_ws != nullptr && ws_size >= need) {
        unsigned short* pscaled = (unsigned short*)d_ws;
        unsigned short* praw    = (unsigned short*)((char*)d_ws + WS_SCALED_B);
        float*          pcv     = (float*)((char*)d_ws + WS_SCALED_B + WS_RAW_B);
        rdm_pack<<<512, 256, 0, stream>>>(node, rel, w, pscaled, praw, pcv);
        rdm4<<<1024, 256, 0, stream>>>(pscaled, praw, pcv, out);
    } else {
        rdm3<<<Bc * Rc * 64, 512, 0, stream>>>(node, rel, w, out);
    }
}

// Round 2
// 68.354 us; speedup vs baseline: 1.7123x; 1.7123x over previous
//
#include <hip/hip_runtime.h>
#include <hip/hip_bf16.h>

// RelationalDistMult: B=8, N=1024, DE=128, R=8, DR=64, D=192.
// scores[b,r,n,m] = sum_k w[r,k]*node[b,n,k]*node[b,m,k] + c[b,r]
//   c[b,r] = sum_d w[r,DE+d]*rel[b,r,d]^2
// out = sigmoid(scores) f32 [B,R,N,N] = 256 MB -> HBM-write-bound
// (fill kernels measure ~7 TB/s => store roofline ~38 us).
//
// Round 5 (post-mortem of the failed pack+compute split):
//  - nt stores bypassed L2 write-combining -> 2.4 TB/s writes. REVERTED to
//    plain stores through write-back L2 (the verified rdm3 path).
//  - Keep the redundancy-elimination idea but INSIDE one kernel: the r-loop
//    moves into the block. Stage RAW tiles once per (b,ntile,mtile):
//    m-rows as bf16 (MFMA A operand), n-rows as f32. Hold all fragments in
//    registers; per r, scale the n-side fragments in-register
//    (f32 mul + v_cvt_pk_bf16_f32, RNE -> same rounding path as rdm3).
//  - Staging L2 reads: 512 MB -> 96 MB; f32->bf16 conversions ~16x fewer;
//    1 barrier per 8 r instead of per r; each wave issues 8 store bursts
//    per block -> stores flow continuously (store-bound regime needs this).
//  - Grid 1024 blocks x 256 thr, block tile 128m x 64n, wave 64m x 32n.
//    VGPR ~190 -> 2 waves/SIMD; LDS 64KB -> 2 blocks/CU = 8 waves/CU.

typedef __attribute__((ext_vector_type(8))) short bf16x8;
typedef __attribute__((ext_vector_type(4))) float f32x4;

constexpr int Bc = 8, Nc = 1024, DEc = 128, Rc = 8, DRc = 64, Dc = 192;

static __device__ __forceinline__ unsigned short f2bf(float x) {
    __hip_bfloat16 h = __float2bfloat16(x);
    return *reinterpret_cast<unsigned short*>(&h);
}

static __device__ __forceinline__ float fast_sigmoid(float x) {
    // sigmoid(x) = 1 / (1 + 2^(-x*log2e)); v_exp_f32 computes 2^x.
    float e;
    asm("v_exp_f32 %0, %1" : "=v"(e) : "v"(x * -1.44269504f));
    float s;
    asm("v_rcp_f32 %0, %1" : "=v"(s) : "v"(e + 1.0f));
    return s;
}

__global__ __launch_bounds__(256, 2) void rdm5(
    const float* __restrict__ node,   // [B,N,DE]
    const float* __restrict__ rel,    // [B,R,DR]
    const float* __restrict__ w,      // [R,D]
    float* __restrict__ out)          // [B,R,N,N]
{
    __shared__ unsigned short Bs[128 * 128];  // raw m-rows, bf16, XOR-swizzled
    __shared__ float          As[64 * 128];   // raw n-rows, f32,  XOR-swizzled
    __shared__ float          cs[8];

    const int lin = blockIdx.x;
    const int b   = lin & 7;          // XCD-major: node[b] (512 KB) L2-resident
    const int q   = lin >> 3;         // 0..127
    const int nt  = q & 15;           // 16 n-tiles of 64
    const int mt  = q >> 4;           // 8  m-tiles of 128
    const int n0  = nt * 64;
    const int m0  = mt * 128;

    const int tid  = threadIdx.x;
    const int lane = tid & 63;
    const int wid  = tid >> 6;        // 0..3
    const int wm0  = (wid >> 1) * 64; // wave m offset in block tile
    const int wn0  = (wid & 1) * 32;  // wave n offset in block tile
    const int lr   = lane & 15;
    const int lk   = (lane >> 4) * 8;

    const float* nodeb = node + (long)b * Nc * DEc;

    // --- c[b, 0..7]: wave 0, lane octet per r, 8 d-elems per lane ---
    if (tid < 64) {
        const int r8 = lane >> 3;
        const int d0 = (lane & 7) * 8;
        const float* wp = w + r8 * Dc + DEc + d0;
        const float* rp = rel + ((long)b * Rc + r8) * DRc + d0;
        float cv = 0.f;
        #pragma unroll
        for (int j = 0; j < 8; ++j) { const float rv = rp[j]; cv += wp[j] * rv * rv; }
        cv += __shfl_xor(cv, 1, 64);
        cv += __shfl_xor(cv, 2, 64);
        cv += __shfl_xor(cv, 4, 64);
        if ((lane & 7) == 0) cs[lane >> 3] = cv;
    }

    // --- stage raw tiles (once per block, reused for all 8 r) ---
    const int col4 = (tid & 31) * 4;  // 0..124 step 4
    const int row0 = tid >> 5;        // 0..7
    #pragma unroll
    for (int p = 0; p < 16; ++p) {    // m-rows -> bf16
        const int row = row0 + p * 8;
        const float4 v = *(const float4*)(nodeb + (long)(m0 + row) * DEc + col4);
        const int e = (row * 128 + col4) ^ ((row & 7) << 3);
        ushort4 u;
        u.x = f2bf(v.x); u.y = f2bf(v.y); u.z = f2bf(v.z); u.w = f2bf(v.w);
        *(ushort4*)&Bs[e] = u;
    }
    #pragma unroll
    for (int p = 0; p < 8; ++p) {     // n-rows -> f32 (scaled per r later)
        const int row = row0 + p * 8;
        const float4 v = *(const float4*)(nodeb + (long)(n0 + row) * DEc + col4);
        const int e = (row * 128 + col4) ^ ((row & 7) << 3);
        *(float4*)&As[e] = v;
    }
    __syncthreads();

    // --- load all fragments into registers (once) ---
    bf16x8 afr[4][4];                 // [kk][mi] raw m fragments (A operand)
    #pragma unroll
    for (int mi = 0; mi < 4; ++mi) {
        const int rowA = wm0 + mi * 16 + lr;
        #pragma unroll
        for (int kk = 0; kk < 4; ++kk)
            afr[kk][mi] = *(const bf16x8*)&Bs[(rowA * 128 + kk * 32 + lk) ^ ((rowA & 7) << 3)];
    }
    f32x4 braw[4][2][2];              // [kk][ni][half] raw n fragments, f32
    #pragma unroll
    for (int ni = 0; ni < 2; ++ni) {
        const int rowB = wn0 + ni * 16 + lr;
        #pragma unroll
        for (int kk = 0; kk < 4; ++kk) {
            const int e = (rowB * 128 + kk * 32 + lk) ^ ((rowB & 7) << 3);
            braw[kk][ni][0] = *(const f32x4*)&As[e];
            braw[kk][ni][1] = *(const f32x4*)&As[e + 4];
        }
    }

    float* outb = out + ((long)b * Rc) * Nc * Nc;

    #pragma unroll 1
    for (int r = 0; r < Rc; ++r) {
        const float c = cs[r];
        const float* wr = w + r * Dc;

        f32x4 acc[4][2] = {};
        #pragma unroll
        for (int kk = 0; kk < 4; ++kk) {
            const f32x4 w0 = *(const f32x4*)(wr + kk * 32 + lk);
            const f32x4 w1 = *(const f32x4*)(wr + kk * 32 + lk + 4);
            bf16x8 bfr[2];
            #pragma unroll
            for (int ni = 0; ni < 2; ++ni) {
                const f32x4 p0 = braw[kk][ni][0] * w0;
                const f32x4 p1 = braw[kk][ni][1] * w1;
                union { bf16x8 v; unsigned int u[4]; } bb;
                asm("v_cvt_pk_bf16_f32 %0, %1, %2" : "=v"(bb.u[0]) : "v"(p0[0]), "v"(p0[1]));
                asm("v_cvt_pk_bf16_f32 %0, %1, %2" : "=v"(bb.u[1]) : "v"(p0[2]), "v"(p0[3]));
                asm("v_cvt_pk_bf16_f32 %0, %1, %2" : "=v"(bb.u[2]) : "v"(p1[0]), "v"(p1[1]));
                asm("v_cvt_pk_bf16_f32 %0, %1, %2" : "=v"(bb.u[3]) : "v"(p1[2]), "v"(p1[3]));
                bfr[ni] = bb.v;
            }
            #pragma unroll
            for (int mi = 0; mi < 4; ++mi)
                #pragma unroll
                for (int ni = 0; ni < 2; ++ni)
                    acc[mi][ni] = __builtin_amdgcn_mfma_f32_16x16x32_bf16(
                        afr[kk][mi], bfr[ni], acc[mi][ni], 0, 0, 0);
        }

        // epilogue: out[n, m]; n = n0+wn0+ni*16+lr, m = m0+wm0+mi*16+(lane>>4)*4+j
        float* outr = outb + ((long)r << 20);
        #pragma unroll
        for (int mi = 0; mi < 4; ++mi) {
            #pragma unroll
            for (int ni = 0; ni < 2; ++ni) {
                const int n = n0 + wn0 + ni * 16 + lr;
                const int m = m0 + wm0 + mi * 16 + (lane >> 4) * 4;
                f32x4 v;
                v[0] = fast_sigmoid(acc[mi][ni][0] + c);
                v[1] = fast_sigmoid(acc[mi][ni][1] + c);
                v[2] = fast_sigmoid(acc[mi][ni][2] + c);
                v[3] = fast_sigmoid(acc[mi][ni][3] + c);
                *(f32x4*)(outr + (long)n * Nc + m) = v;  // plain store (L2 WB)
            }
        }
    }
}

extern "C" void kernel_launch(void* const* d_in, const int* in_sizes, int n_in,
                              void* d_out, int out_size, void* d_ws, size_t ws_size,
                              hipStream_t stream) {
    const float* node = (const float*)d_in[0];  // [8,1024,128]
    const float* rel  = (const float*)d_in[1];  // [8,8,64]
    const float* w    = (const float*)d_in[2];  // [8,192]
    float* out = (float*)d_out;                 // [8,8,1024,1024]

    rdm5<<<1024, 256, 0, stream>>>(node, rel, w, out);
}

// Round 3
// 63.229 us; speedup vs baseline: 1.8511x; 1.0810x over previous
//
#include <hip/hip_runtime.h>
#include <hip/hip_bf16.h>

// RelationalDistMult: B=8, N=1024, DE=128, R=8, DR=64, D=192.
// scores[b,r,n,m] = sum_k w[r,k]*node[b,n,k]*node[b,m,k] + c[b,r]
//   c[b,r] = sum_d w[r,DE+d]*rel[b,r,d]^2
// out = sigmoid(scores) f32 [B,R,N,N] = 256 MB -> HBM-write-bound
// (fill kernels measure ~7 TB/s => store roofline ~38 us).
//
// Round 6 = rdm3 (verified 64.7 us) + ONE change: full-line coalesced stores.
// Post-mortem r1/r2: rdm3 (LDS-heavy, 16 waves/CU) and rdm5 (reg-heavy,
// 8 waves/CU) both land ~65 us -> limiter is common: the store pattern.
// Old epilogue: each f32x4 store instr = 16 scattered 64B segments (half
// cache lines) -> 2x L2 write transactions + partial-line allocate traffic.
// New epilogue: wave result (64m x 32n) bounces through a per-wave padded
// LDS buffer [32][68] f32 (exactly 8 words/bank per access -> conflict-free
// both directions), then is stored in store-major order: each instruction
// writes 4 n-rows x 256 B contiguous = 8 COMPLETE 128B lines.
// Same store instruction count; LDS 64->68 KB (still 2 blocks/CU).

typedef __attribute__((ext_vector_type(8))) short bf16x8;
typedef __attribute__((ext_vector_type(4))) float f32x4;

constexpr int Bc = 8, Nc = 1024, DEc = 128, Rc = 8, DRc = 64, Dc = 192;
constexpr int TILE = 128;

static __device__ __forceinline__ unsigned short f2bf(float x) {
    __hip_bfloat16 h = __float2bfloat16(x);
    return *reinterpret_cast<unsigned short*>(&h);
}

static __device__ __forceinline__ float fast_sigmoid(float x) {
    // sigmoid(x) = 1 / (1 + 2^(-x*log2e)); v_exp_f32 computes 2^x.
    float e;
    asm("v_exp_f32 %0, %1" : "=v"(e) : "v"(x * -1.44269504f));
    float s;
    asm("v_rcp_f32 %0, %1" : "=v"(s) : "v"(e + 1.0f));
    return s;
}

__global__ __launch_bounds__(512, 4) void rdm6(
    const float* __restrict__ node,   // [B,N,DE]
    const float* __restrict__ rel,    // [B,R,DR]
    const float* __restrict__ w,      // [R,D]
    float* __restrict__ out)          // [B,R,N,N]
{
    // Phase 1 alias: As/Bs bf16 tiles (64 KB). Phase 2 alias: per-wave
    // transpose buffers, 8 waves x [32][68] f32 = 69632 B.
    __shared__ float smem[17408];
    unsigned short* As = (unsigned short*)smem;           // scaled n-rows
    unsigned short* Bs = (unsigned short*)smem + 16384;   // raw m-rows

    const int lin = blockIdx.x;
    const int b   = lin & 7;          // XCD-major: one batch per XCD
    const int r   = (lin >> 3) & 7;
    const int t   = lin >> 6;         // 0..63
    const int ntile = t >> 3;
    const int mtile = t & 7;
    const int n0 = ntile * TILE;
    const int m0 = mtile * TILE;

    const int tid  = threadIdx.x;
    const int lane = tid & 63;
    const int wid  = tid >> 6;        // 0..7

    const float* wrp   = w + r * Dc;
    const float* relbr = rel + ((long)b * Rc + r) * DRc;

    // --- c[b,r]: lane-parallel (DR=64 = wave width) + butterfly reduce ---
    float cv = wrp[DEc + lane] * relbr[lane] * relbr[lane];
    #pragma unroll
    for (int o = 32; o > 0; o >>= 1) cv += __shfl_xor(cv, o, 64);
    const float c = cv;

    // --- stage: global f32 -> bf16 -> XOR-swizzled LDS ---
    const float* nodeb = node + (long)b * Nc * DEc;
    const int col4 = (tid & 31) * 4;  // 0..127 step 4
    const int row0 = tid >> 5;        // 0..15
    const float4 wv4 = *(const float4*)(wrp + col4);

    #pragma unroll
    for (int p = 0; p < 8; ++p) {
        const int row = row0 + p * 16;
        const float4 av = *(const float4*)(nodeb + (long)(n0 + row) * DEc + col4);
        const float4 bv = *(const float4*)(nodeb + (long)(m0 + row) * DEc + col4);
        const int e = (row * TILE + col4) ^ ((row & 7) << 3);
        union { ushort4 u4; unsigned short h[4]; } pa, pb;
        pa.h[0] = f2bf(av.x * wv4.x);
        pa.h[1] = f2bf(av.y * wv4.y);
        pa.h[2] = f2bf(av.z * wv4.z);
        pa.h[3] = f2bf(av.w * wv4.w);
        pb.h[0] = f2bf(bv.x);
        pb.h[1] = f2bf(bv.y);
        pb.h[2] = f2bf(bv.z);
        pb.h[3] = f2bf(bv.w);
        *(ushort4*)&As[e] = pa.u4;
        *(ushort4*)&Bs[e] = pb.u4;
    }
    __syncthreads();

    // --- MFMA: 8 waves in 2(m) x 4(n); each wave: 64(m) x 32(n) tile ---
    const int wm0 = (wid >> 2) * 64;  // m offset within tile
    const int wn0 = (wid & 3) * 32;   // n offset within tile
    const int lr  = lane & 15;
    const int lk  = (lane >> 4) * 8;

    f32x4 acc[4][2] = {};

    #pragma unroll
    for (int kk = 0; kk < 4; ++kk) {  // K = 128 in 4 steps of 32
        bf16x8 afr[4], bfr[2];
        #pragma unroll
        for (int mi = 0; mi < 4; ++mi) {
            const int rowA = wm0 + mi * 16 + lr;           // raw m-row
            afr[mi] = *(const bf16x8*)&Bs[(rowA * TILE + kk * 32 + lk) ^ ((rowA & 7) << 3)];
        }
        #pragma unroll
        for (int ni = 0; ni < 2; ++ni) {
            const int rowB = wn0 + ni * 16 + lr;           // scaled n-row
            bfr[ni] = *(const bf16x8*)&As[(rowB * TILE + kk * 32 + lk) ^ ((rowB & 7) << 3)];
        }
        #pragma unroll
        for (int mi = 0; mi < 4; ++mi)
            #pragma unroll
            for (int ni = 0; ni < 2; ++ni)
                acc[mi][ni] = __builtin_amdgcn_mfma_f32_16x16x32_bf16(
                    afr[mi], bfr[ni], acc[mi][ni], 0, 0, 0);
    }

    // all waves done reading As/Bs before we overwrite the LDS
    __syncthreads();

    // --- epilogue: sigmoid -> per-wave LDS transpose -> full-line stores ---
    // MFMA D layout: n = wn0+ni*16+(lane&15), m = wm0+mi*16+(lane>>4)*4+j.
    float* tb = smem + wid * (32 * 68);   // per-wave [32 n][68 m-words]

    #pragma unroll
    for (int mi = 0; mi < 4; ++mi) {
        #pragma unroll
        for (int ni = 0; ni < 2; ++ni) {
            const int n_t = ni * 16 + lr;
            const int m_t = mi * 16 + (lane >> 4) * 4;
            f32x4 v;
            v[0] = fast_sigmoid(acc[mi][ni][0] + c);
            v[1] = fast_sigmoid(acc[mi][ni][1] + c);
            v[2] = fast_sigmoid(acc[mi][ni][2] + c);
            v[3] = fast_sigmoid(acc[mi][ni][3] + c);
            *(f32x4*)&tb[n_t * 68 + m_t] = v;
        }
    }
    asm volatile("s_waitcnt lgkmcnt(0)" ::: "memory");

    // store-major read-back: instr p covers 4 n-rows x 256 B contiguous
    float* outbr = out + (long)(b * Rc + r) * Nc * Nc
                 + (long)(n0 + wn0) * Nc + (m0 + wm0);
    #pragma unroll
    for (int p = 0; p < 8; ++p) {
        const int n_t = p * 4 + (lane >> 4);
        const int m_t = (lane & 15) * 4;
        const f32x4 v = *(const f32x4*)&tb[n_t * 68 + m_t];
        *(f32x4*)(outbr + (long)n_t * Nc + m_t) = v;
    }
}

extern "C" void kernel_launch(void* const* d_in, const int* in_sizes, int n_in,
                              void* d_out, int out_size, void* d_ws, size_t ws_size,
                              hipStream_t stream) {
    const float* node = (const float*)d_in[0];  // [8,1024,128]
    const float* rel  = (const float*)d_in[1];  // [8,8,64]
    const float* w    = (const float*)d_in[2];  // [8,192]
    float* out = (float*)d_out;                 // [8,8,1024,1024]

    rdm6<<<Bc * Rc * 64, 512, 0, stream>>>(node, rel, w, out);
}

// Round 4
// 56.849 us; speedup vs baseline: 2.0588x; 1.1122x over previous
//
#include <hip/hip_runtime.h>
#include <hip/hip_bf16.h>

// RelationalDistMult: B=8, N=1024, DE=128, R=8, DR=64, D=192.
// scores[b,r,n,m] = sum_k w[r,k]*node[b,n,k]*node[b,m,k] + c[b,r]
//   c[b,r] = sum_d w[r,DE+d]*rel[b,r,d]^2
// out = sigmoid(scores) f32 [B,R,N,N] = 256 MB -> HBM-write-bound
// (fill kernels measure ~7 TB/s => store roofline ~38 us).
//
// Round 7: SYMMETRY. scores[n,m] == scores[m,n] (diag bilinear + c both
// symmetric), so compute only tile-pairs ntile<=mtile (36/64 per (b,r)),
// grid 4096 -> 2304, and store each off-diagonal tile TWICE (direct +
// transposed). Bytes written unchanged (2016*128KB + 288*64KB = 268 MB);
// ALL non-store work (stage reads, f2bf converts, MFMA, sigmoid, barriers)
// drops x0.5625 -> store-issue density per block ~doubles. r1-r3 showed
// stores can't reach fill-rate because non-store phases starve the write
// stream; this attacks exactly that ratio.
//  - direct store: rdm6's LDS-transpose full-line path (4 n-rows x 256 B
//    per instr = 8 complete lines).
//  - transposed store: read per-wave buffer in the other orientation
//    (4x ds_read_b32 gather, 4-way bank conflict, cheap) -> 8 m-rows x
//    128 B per instr = 8 complete lines.

typedef __attribute__((ext_vector_type(8))) short bf16x8;
typedef __attribute__((ext_vector_type(4))) float f32x4;

constexpr int Bc = 8, Nc = 1024, DEc = 128, Rc = 8, DRc = 64, Dc = 192;
constexpr int TILE = 128;

static __device__ __forceinline__ unsigned short f2bf(float x) {
    __hip_bfloat16 h = __float2bfloat16(x);
    return *reinterpret_cast<unsigned short*>(&h);
}

static __device__ __forceinline__ float fast_sigmoid(float x) {
    // sigmoid(x) = 1 / (1 + 2^(-x*log2e)); v_exp_f32 computes 2^x.
    float e;
    asm("v_exp_f32 %0, %1" : "=v"(e) : "v"(x * -1.44269504f));
    float s;
    asm("v_rcp_f32 %0, %1" : "=v"(s) : "v"(e + 1.0f));
    return s;
}

__global__ __launch_bounds__(512, 4) void rdm7(
    const float* __restrict__ node,   // [B,N,DE]
    const float* __restrict__ rel,    // [B,R,DR]
    const float* __restrict__ w,      // [R,D]
    float* __restrict__ out)          // [B,R,N,N]
{
    // Phase 1 alias: As/Bs bf16 tiles (64 KB). Phase 2 alias: per-wave
    // transpose buffers, 8 waves x [32 n][68 m] f32 = 69632 B.
    __shared__ float smem[17408];
    unsigned short* As = (unsigned short*)smem;           // scaled n-rows
    unsigned short* Bs = (unsigned short*)smem + 16384;   // raw m-rows

    const int lin  = blockIdx.x;
    const int b    = lin & 7;         // XCD-major: one batch per XCD
    const int rest = lin >> 3;        // 0..287
    const int r    = rest & 7;
    const int tp   = rest >> 3;       // 0..35 upper-tri tile pair

    // tp -> (i=ntile, j=mtile) with i<=j over 8 tiles
    int i = 0, acc0 = 0;
    while (tp >= acc0 + (8 - i)) { acc0 += 8 - i; ++i; }
    const int j = i + (tp - acc0);
    const int n0 = i * TILE;
    const int m0 = j * TILE;
    const bool offdiag = (i != j);

    const int tid  = threadIdx.x;
    const int lane = tid & 63;
    const int wid  = tid >> 6;        // 0..7

    const float* wrp   = w + r * Dc;
    const float* relbr = rel + ((long)b * Rc + r) * DRc;

    // --- c[b,r]: lane-parallel (DR=64 = wave width) + butterfly reduce ---
    float cv = wrp[DEc + lane] * relbr[lane] * relbr[lane];
    #pragma unroll
    for (int o = 32; o > 0; o >>= 1) cv += __shfl_xor(cv, o, 64);
    const float c = cv;

    // --- stage: global f32 -> bf16 -> XOR-swizzled LDS ---
    const float* nodeb = node + (long)b * Nc * DEc;
    const int col4 = (tid & 31) * 4;  // 0..127 step 4
    const int row0 = tid >> 5;        // 0..15
    const float4 wv4 = *(const float4*)(wrp + col4);

    #pragma unroll
    for (int p = 0; p < 8; ++p) {
        const int row = row0 + p * 16;
        const float4 av = *(const float4*)(nodeb + (long)(n0 + row) * DEc + col4);
        const float4 bv = *(const float4*)(nodeb + (long)(m0 + row) * DEc + col4);
        const int e = (row * TILE + col4) ^ ((row & 7) << 3);
        union { ushort4 u4; unsigned short h[4]; } pa, pb;
        pa.h[0] = f2bf(av.x * wv4.x);
        pa.h[1] = f2bf(av.y * wv4.y);
        pa.h[2] = f2bf(av.z * wv4.z);
        pa.h[3] = f2bf(av.w * wv4.w);
        pb.h[0] = f2bf(bv.x);
        pb.h[1] = f2bf(bv.y);
        pb.h[2] = f2bf(bv.z);
        pb.h[3] = f2bf(bv.w);
        *(ushort4*)&As[e] = pa.u4;
        *(ushort4*)&Bs[e] = pb.u4;
    }
    __syncthreads();

    // --- MFMA: 8 waves in 2(m) x 4(n); each wave: 64(m) x 32(n) tile ---
    const int wm0 = (wid >> 2) * 64;  // m offset within tile
    const int wn0 = (wid & 3) * 32;   // n offset within tile
    const int lr  = lane & 15;
    const int lk  = (lane >> 4) * 8;

    f32x4 acc[4][2] = {};

    #pragma unroll
    for (int kk = 0; kk < 4; ++kk) {  // K = 128 in 4 steps of 32
        bf16x8 afr[4], bfr[2];
        #pragma unroll
        for (int mi = 0; mi < 4; ++mi) {
            const int rowA = wm0 + mi * 16 + lr;           // raw m-row
            afr[mi] = *(const bf16x8*)&Bs[(rowA * TILE + kk * 32 + lk) ^ ((rowA & 7) << 3)];
        }
        #pragma unroll
        for (int ni = 0; ni < 2; ++ni) {
            const int rowB = wn0 + ni * 16 + lr;           // scaled n-row
            bfr[ni] = *(const bf16x8*)&As[(rowB * TILE + kk * 32 + lk) ^ ((rowB & 7) << 3)];
        }
        #pragma unroll
        for (int mi = 0; mi < 4; ++mi)
            #pragma unroll
            for (int ni = 0; ni < 2; ++ni)
                acc[mi][ni] = __builtin_amdgcn_mfma_f32_16x16x32_bf16(
                    afr[mi], bfr[ni], acc[mi][ni], 0, 0, 0);
    }

    // all waves done reading As/Bs before we overwrite the LDS
    __syncthreads();

    // --- epilogue: sigmoid -> per-wave LDS buffer tb[32 n][68 m] ---
    // MFMA D layout: n = wn0+ni*16+(lane&15), m = wm0+mi*16+(lane>>4)*4+j.
    float* tb = smem + wid * (32 * 68);

    #pragma unroll
    for (int mi = 0; mi < 4; ++mi) {
        #pragma unroll
        for (int ni = 0; ni < 2; ++ni) {
            const int n_t = ni * 16 + lr;
            const int m_t = mi * 16 + (lane >> 4) * 4;
            f32x4 v;
            v[0] = fast_sigmoid(acc[mi][ni][0] + c);
            v[1] = fast_sigmoid(acc[mi][ni][1] + c);
            v[2] = fast_sigmoid(acc[mi][ni][2] + c);
            v[3] = fast_sigmoid(acc[mi][ni][3] + c);
            *(f32x4*)&tb[n_t * 68 + m_t] = v;
        }
    }
    asm volatile("s_waitcnt lgkmcnt(0)" ::: "memory");

    float* plane = out + (long)(b * Rc + r) * Nc * Nc;

    // --- direct store: instr p covers 4 n-rows x 256 B = 8 complete lines ---
    {
        float* outd = plane + (long)(n0 + wn0) * Nc + (m0 + wm0);
        #pragma unroll
        for (int p = 0; p < 8; ++p) {
            const int n_t = p * 4 + (lane >> 4);
            const int m_t = (lane & 15) * 4;
            const f32x4 v = *(const f32x4*)&tb[n_t * 68 + m_t];
            *(f32x4*)(outd + (long)n_t * Nc + m_t) = v;
        }
    }

    // --- transposed store (off-diag only): out[m, n] = tile(n, m) ---
    // instr p covers 8 m-rows x 128 B = 8 complete lines.
    if (offdiag) {
        float* outt = plane + (long)(m0 + wm0) * Nc + (n0 + wn0);
        #pragma unroll
        for (int p = 0; p < 8; ++p) {
            const int m_t = p * 8 + (lane >> 3);   // 0..63 within wave m-span
            const int n_t = (lane & 7) * 4;        // 0..28 within wave n-span
            f32x4 v;
            v[0] = tb[(n_t + 0) * 68 + m_t];
            v[1] = tb[(n_t + 1) * 68 + m_t];
            v[2] = tb[(n_t + 2) * 68 + m_t];
            v[3] = tb[(n_t + 3) * 68 + m_t];
            *(f32x4*)(outt + (long)m_t * Nc + n_t) = v;
        }
    }
}

extern "C" void kernel_launch(void* const* d_in, const int* in_sizes, int n_in,
                              void* d_out, int out_size, void* d_ws, size_t ws_size,
                              hipStream_t stream) {
    const float* node = (const float*)d_in[0];  // [8,1024,128]
    const float* rel  = (const float*)d_in[1];  // [8,8,64]
    const float* w    = (const float*)d_in[2];  // [8,192]
    float* out = (float*)d_out;                 // [8,8,1024,1024]

    rdm7<<<Bc * Rc * 36, 512, 0, stream>>>(node, rel, w, out);
}